// Round 7
// baseline (260.187 us; speedup 1.0000x reference)
//
#include <hip/hip_runtime.h>
#include <math.h>

#define B_ 2
#define T_ 1024
#define D_ 1024
#define H_ 16

typedef __attribute__((ext_vector_type(8))) short bf16x8;
typedef __attribute__((ext_vector_type(4))) float f32x4;

__device__ inline unsigned short f2bf(float x) {
  return (unsigned short)((__float_as_uint(x) + 0x8000u) >> 16);
}
// pack two f32 -> dword of 2 bf16 (lo in low half)
__device__ inline unsigned bfpack(float lo, float hi) {
  unsigned a = __float_as_uint(hi) + 0x8000u;
  unsigned b = __float_as_uint(lo) + 0x8000u;
  return __builtin_amdgcn_perm(a, b, 0x07060302);
}
__device__ inline void hl_split(float x, unsigned short& h, unsigned short& l) {
  unsigned short hh = f2bf(x);
  float hf = __uint_as_float(((unsigned)hh) << 16);
  l = f2bf(x - hf);
  h = hh;
}

// ================= f32 -> bf16 conversion (x, concat-W, Wout) =================
#define CN1 2097152   // x
#define CN2 3407872   // Wb = [Wqkv;W1w;W2w;W1r;W2r] 3328x1024
#define CN3 1048576   // Wout
__global__ __launch_bounds__(256) void convert_kernel(
    const float* __restrict__ x, const float* __restrict__ Wqkv,
    const float* __restrict__ W1w, const float* __restrict__ W2w,
    const float* __restrict__ W1r, const float* __restrict__ W2r,
    const float* __restrict__ Wout,
    unsigned short* __restrict__ xb, unsigned short* __restrict__ Wb,
    unsigned short* __restrict__ Woutb)
{
  const long i8 = ((long)blockIdx.x * 256 + threadIdx.x) * 8;
  const float* src;
  unsigned short* dst;
  if (i8 < CN1) {
    src = x + i8; dst = xb + i8;
  } else if (i8 < CN1 + CN2) {
    const long j = i8 - CN1;
    const int row = (int)(j >> 10), col = (int)(j & 1023);
    if (row < 3072) src = Wqkv + (size_t)row * 1024 + col;
    else {
      const int r = row - 3072;
      const float* Wm = (r < 64) ? W1w : (r < 128) ? W2w : (r < 192) ? W1r : W2r;
      src = Wm + (size_t)(r & 63) * 1024 + col;
    }
    dst = Wb + j;
  } else {
    const long j = i8 - CN1 - CN2;
    src = Wout + j; dst = Woutb + j;
  }
  const float4 v0 = *(const float4*)src;
  const float4 v1 = *(const float4*)(src + 4);
  uint4 o;
  o.x = bfpack(v0.x, v0.y); o.y = bfpack(v0.z, v0.w);
  o.z = bfpack(v1.x, v1.y); o.w = bfpack(v1.z, v1.w);
  *(uint4*)dst = o;
}

// =================== bf16 MFMA GEMM core (128x64 tile, 2 waves, BK=32) ===================
// LDS slot-major: As[2][4 slot][128 row][16B], Bs[2][4 slot][64 row][16B] -> 2-way reads.
#define G_PRO()                                                                \
  const int tid = threadIdx.x;                                                 \
  const int w = tid >> 6, lane = tid & 63;                                     \
  const int lr = lane & 15, g = lane >> 4;                                     \
  const int wm = w * 64;                                                       \
  const int brow = tid & 63, bhalf = tid >> 6;

#define G_LOADA(d, s) {                                                        \
  d[0] = *(const uint4*)(Ap + (s) * 32);                                       \
  d[1] = *(const uint4*)(Ap + (s) * 32 + 8);                                   \
  d[2] = *(const uint4*)(Ap + (s) * 32 + 16);                                  \
  d[3] = *(const uint4*)(Ap + (s) * 32 + 24); }
#define G_LOADB(d, s) {                                                        \
  d[0] = *(const uint4*)(Bp + (s) * 32);                                       \
  d[1] = *(const uint4*)(Bp + (s) * 32 + 8); }
#define G_STORE(bi, a, b) {                                                    \
  unsigned char* SA_ = As + (bi) * 8192;                                       \
  *(uint4*)(SA_ + 0 * 2048 + tid * 16) = a[0];                                 \
  *(uint4*)(SA_ + 1 * 2048 + tid * 16) = a[1];                                 \
  *(uint4*)(SA_ + 2 * 2048 + tid * 16) = a[2];                                 \
  *(uint4*)(SA_ + 3 * 2048 + tid * 16) = a[3];                                 \
  unsigned char* SB_ = Bs + (bi) * 4096;                                       \
  *(uint4*)(SB_ + (2 * bhalf) * 1024 + brow * 16) = b[0];                      \
  *(uint4*)(SB_ + (2 * bhalf + 1) * 1024 + brow * 16) = b[1]; }
#define G_COMPUTE(bi) {                                                        \
  const unsigned char* SA_ = As + (bi) * 8192;                                 \
  const unsigned char* SB_ = Bs + (bi) * 4096;                                 \
  bf16x8 af[4], bfr[4];                                                        \
  _Pragma("unroll") for (int i = 0; i < 4; ++i)                                \
    af[i] = *(const bf16x8*)(SA_ + g * 2048 + (wm + i * 16 + lr) * 16);        \
  _Pragma("unroll") for (int j = 0; j < 4; ++j)                                \
    bfr[j] = *(const bf16x8*)(SB_ + g * 1024 + (j * 16 + lr) * 16);            \
  _Pragma("unroll") for (int i = 0; i < 4; ++i)                                \
  _Pragma("unroll") for (int j = 0; j < 4; ++j)                                \
    acc[i][j] = __builtin_amdgcn_mfma_f32_16x16x32_bf16(af[i], bfr[j],         \
                                                        acc[i][j], 0, 0, 0); }
#define G_MAIN()                                                               \
  f32x4 acc[4][4];                                                             \
  const f32x4 zf = {0.f, 0.f, 0.f, 0.f};                                       \
  _Pragma("unroll") for (int i = 0; i < 4; ++i)                                \
  _Pragma("unroll") for (int j = 0; j < 4; ++j) acc[i][j] = zf;                \
  uint4 a0[4], b0[2], a1[4], b1[2];                                            \
  G_LOADA(a0, 0); G_LOADB(b0, 0);                                              \
  G_STORE(0, a0, b0);                                                          \
  G_LOADA(a1, 1); G_LOADB(b1, 1);                                              \
  __syncthreads();                                                             \
  _Pragma("unroll 1") for (int s = 0; s < 32; s += 2) {                        \
    G_COMPUTE(0);                                                              \
    G_STORE(1, a1, b1);                                                        \
    if (s + 2 < 32) { G_LOADA(a0, s + 2); G_LOADB(b0, s + 2); }                \
    __syncthreads();                                                           \
    G_COMPUTE(1);                                                              \
    if (s + 2 < 32) G_STORE(0, a0, b0);                                        \
    if (s + 3 < 32) { G_LOADA(a1, s + 3); G_LOADB(b1, s + 3); }                \
    __syncthreads();                                                           \
  }

// qkv GEMM: [2048,3328] = xb @ Wb^T; cols<3072 -> qkvb (bf16, +bias), else linesf (f32)
__global__ __launch_bounds__(128) void gemm_qkv(
    const unsigned short* __restrict__ Ab, const unsigned short* __restrict__ Bb,
    const float* __restrict__ bqkv,
    unsigned short* __restrict__ Cq, float* __restrict__ Clines)
{
  __shared__ __align__(16) unsigned char As[2 * 8192];
  __shared__ __align__(16) unsigned char Bs[2 * 4096];
  const int bid = blockIdx.x;                    // 832 = 16m x 52n
  const int sid = (bid & 7) * 104 + (bid >> 3);  // bijective XCD swizzle
  const int m0 = (sid & 15) * 128, n0 = (sid >> 4) * 64;
  G_PRO();
  const unsigned short* Ap = Ab + (size_t)(m0 + tid) * 1024;
  const unsigned short* Bp = Bb + (size_t)(n0 + brow) * 1024 + bhalf * 16;
  G_MAIN();
#pragma unroll
  for (int i = 0; i < 4; ++i) {
    const int rbase = m0 + wm + i * 16 + 4 * g;
#pragma unroll
    for (int j = 0; j < 4; ++j) {
      const int col = n0 + j * 16 + lr;
      if (col < 3072) {
        const float bb = bqkv[col];
#pragma unroll
        for (int r = 0; r < 4; ++r)
          Cq[(size_t)(rbase + r) * 3072 + col] = f2bf(acc[i][j][r] + bb);
      } else {
#pragma unroll
        for (int r = 0; r < 4; ++r)
          Clines[(size_t)(rbase + r) * 256 + col - 3072] = acc[i][j][r];
      }
    }
  }
}

// out GEMM: [2048,1024] f32 = attnb @ Woutb^T + bout
__global__ __launch_bounds__(128) void gemm_out(
    const unsigned short* __restrict__ Ab, const unsigned short* __restrict__ Bb,
    const float* __restrict__ bias, float* __restrict__ C)
{
  __shared__ __align__(16) unsigned char As[2 * 8192];
  __shared__ __align__(16) unsigned char Bs[2 * 4096];
  const int bid = blockIdx.x;                   // 256 = 16m x 16n
  const int sid = (bid & 7) * 32 + (bid >> 3);
  const int m0 = (sid & 15) * 128, n0 = (sid >> 4) * 64;
  G_PRO();
  const unsigned short* Ap = Ab + (size_t)(m0 + tid) * 1024;
  const unsigned short* Bp = Bb + (size_t)(n0 + brow) * 1024 + bhalf * 16;
  G_MAIN();
#pragma unroll
  for (int i = 0; i < 4; ++i) {
    const int rbase = m0 + wm + i * 16 + 4 * g;
#pragma unroll
    for (int j = 0; j < 4; ++j) {
      const int col = n0 + j * 16 + lr;
      const float bb = bias[col];
#pragma unroll
      for (int r = 0; r < 4; ++r)
        C[(size_t)(rbase + r) * 1024 + col] = acc[i][j][r] + bb;
    }
  }
}

// ============ exterior products + J6 permute from linesf ============
__global__ __launch_bounds__(256) void exterior_kernel(
    const float* __restrict__ linesf,
    float* __restrict__ Jw, float* __restrict__ rd,
    unsigned* __restrict__ Jwpk)
{
  const int i = blockIdx.x * 256 + threadIdx.x;   // 32768
  const int h = i & 15;
  const int t = (i >> 4) & 1023;
  const int b = i >> 14;
  const size_t rowt = ((size_t)(b * T_) + t) * 256;

  float4 p1w = make_float4(0.f, 0.f, 0.f, 0.f);
  if (t > 0) p1w = *(const float4*)(linesf + rowt - 256 + h * 4);
  const float4 p2w = *(const float4*)(linesf + rowt + 64 + h * 4);
  const float4 p1r = *(const float4*)(linesf + rowt + 128 + h * 4);
  const float4 p2r = *(const float4*)(linesf + rowt + 192 + h * 4);

  const size_t base = ((size_t)(b * H_ + h) * T_ + t) * 6;
  {
    const float L0 = p1w.x * p2w.y - p1w.y * p2w.x;
    const float L1 = p1w.x * p2w.z - p1w.z * p2w.x;
    const float L2 = p1w.x * p2w.w - p1w.w * p2w.x;
    const float L3 = p1w.y * p2w.z - p1w.z * p2w.y;
    const float L4 = p1w.y * p2w.w - p1w.w * p2w.y;
    const float L5 = p1w.z * p2w.w - p1w.w * p2w.z;
    const float n = sqrtf(L0 * L0 + L1 * L1 + L2 * L2 + L3 * L3 + L4 * L4 + L5 * L5);
    const float inv = 1.f / fmaxf(n, 1e-12f);
    float jv[6] = {L5 * inv, -L4 * inv, L3 * inv, L2 * inv, -L1 * inv, L0 * inv};
#pragma unroll
    for (int k = 0; k < 6; ++k) Jw[base + k] = jv[k];
    unsigned short JH[6], JL[6];
#pragma unroll
    for (int k = 0; k < 6; ++k) hl_split(jv[k], JH[k], JL[k]);
    unsigned* jp = Jwpk + (((size_t)(b * H_ + h) * T_ + t) << 4);
    unsigned h01 = JH[0] | ((unsigned)JH[1] << 16);
    unsigned h23 = JH[2] | ((unsigned)JH[3] << 16);
    unsigned h45 = JH[4] | ((unsigned)JH[5] << 16);
    jp[0] = h01; jp[1] = h23; jp[2] = h45;
    jp[3] = JL[0] | ((unsigned)JL[1] << 16);
    jp[4] = JL[2] | ((unsigned)JL[3] << 16);
    jp[5] = JL[4] | ((unsigned)JL[5] << 16);
    jp[6] = h01; jp[7] = h23; jp[8] = h45;
#pragma unroll
    for (int k = 9; k < 16; ++k) jp[k] = 0;
  }
  {
    const float L0 = p1r.x * p2r.y - p1r.y * p2r.x;
    const float L1 = p1r.x * p2r.z - p1r.z * p2r.x;
    const float L2 = p1r.x * p2r.w - p1r.w * p2r.x;
    const float L3 = p1r.y * p2r.z - p1r.z * p2r.y;
    const float L4 = p1r.y * p2r.w - p1r.w * p2r.y;
    const float L5 = p1r.z * p2r.w - p1r.w * p2r.z;
    const float n = sqrtf(L0 * L0 + L1 * L1 + L2 * L2 + L3 * L3 + L4 * L4 + L5 * L5);
    const float inv = 1.f / fmaxf(n, 1e-12f);
    rd[base + 0] = L0 * inv;
    rd[base + 1] = L1 * inv;
    rd[base + 2] = L2 * inv;
    rd[base + 3] = L3 * inv;
    rd[base + 4] = L4 * inv;
    rd[base + 5] = L5 * inv;
  }
}

// ============ causal 6x6 Gram cumsum (Hillis-Steele) + rd_M -> rdMpk ============
__global__ __launch_bounds__(256) void scan_kernel(
    const float* __restrict__ Jw, const float* __restrict__ rd,
    unsigned* __restrict__ rdMpk)
{
  __shared__ float sc[256][40];   // 160B rows (16B-aligned, bank-spread)
  const int tid = threadIdx.x;
  const int bh = blockIdx.x;
  const float* Jb = Jw + (size_t)bh * T_ * 6;
  const float* Rb = rd + (size_t)bh * T_ * 6;
  const int t0 = tid * 4;

  float L[36], M[36];
#pragma unroll
  for (int i = 0; i < 36; ++i) L[i] = 0.f;
  for (int tt = 0; tt < 4; ++tt) {
    float j6[6];
#pragma unroll
    for (int i = 0; i < 6; ++i) j6[i] = Jb[(size_t)(t0 + tt) * 6 + i];
#pragma unroll
    for (int a = 0; a < 6; ++a)
#pragma unroll
      for (int c = 0; c < 6; ++c)
        L[a * 6 + c] = fmaf(j6[a], j6[c], L[a * 6 + c]);
  }
#pragma unroll
  for (int i = 0; i < 36; ++i) M[i] = L[i];
#pragma unroll
  for (int k = 0; k < 9; ++k)
    *(float4*)&sc[tid][k * 4] = make_float4(M[k*4], M[k*4+1], M[k*4+2], M[k*4+3]);
  __syncthreads();

  for (int off = 1; off < 256; off <<= 1) {
    float4 tmp[9];
    const bool act = (tid >= off);
    if (act) {
#pragma unroll
      for (int k = 0; k < 9; ++k) tmp[k] = *(const float4*)&sc[tid - off][k * 4];
    }
    __syncthreads();
    if (act) {
#pragma unroll
      for (int k = 0; k < 9; ++k) {
        M[k*4]   += tmp[k].x; M[k*4+1] += tmp[k].y;
        M[k*4+2] += tmp[k].z; M[k*4+3] += tmp[k].w;
      }
#pragma unroll
      for (int k = 0; k < 9; ++k)
        *(float4*)&sc[tid][k * 4] = make_float4(M[k*4], M[k*4+1], M[k*4+2], M[k*4+3]);
    }
    __syncthreads();
  }

  float Mp[36];
#pragma unroll
  for (int i = 0; i < 36; ++i) Mp[i] = M[i] - L[i];   // exclusive prefix

  for (int tt = 0; tt < 4; ++tt) {
    const int t = t0 + tt;
    float j6[6], r6[6];
#pragma unroll
    for (int i = 0; i < 6; ++i) { j6[i] = Jb[(size_t)t * 6 + i]; r6[i] = Rb[(size_t)t * 6 + i]; }
#pragma unroll
    for (int a = 0; a < 6; ++a)
#pragma unroll
      for (int c = 0; c < 6; ++c)
        Mp[a * 6 + c] = fmaf(j6[a], j6[c], Mp[a * 6 + c]);
    float s6[6];
#pragma unroll
    for (int jj = 0; jj < 6; ++jj) {
      float s = 0.f;
#pragma unroll
      for (int a = 0; a < 6; ++a) s = fmaf(r6[a], Mp[a * 6 + jj], s);
      s6[jj] = s;
    }
    unsigned short hh[6], ll[6];
#pragma unroll
    for (int i = 0; i < 6; ++i) hl_split(s6[i], hh[i], ll[i]);
    unsigned* ob = rdMpk + (((size_t)bh * T_ + t) << 4);
    unsigned h01 = hh[0] | ((unsigned)hh[1] << 16);
    unsigned h23 = hh[2] | ((unsigned)hh[3] << 16);
    unsigned h45 = hh[4] | ((unsigned)hh[5] << 16);
    ob[0] = h01; ob[1] = h23; ob[2] = h45;
    ob[3] = h01; ob[4] = h23; ob[5] = h45;
    ob[6] = ll[0] | ((unsigned)ll[1] << 16);
    ob[7] = ll[2] | ((unsigned)ll[3] << 16);
    ob[8] = ll[4] | ((unsigned)ll[5] << 16);
#pragma unroll
    for (int i = 9; i < 16; ++i) ob[i] = 0;
  }
}

// ============ MFMA flash attention (bf16 qkv, direct-global K/Q/Jw) ============
// LDS: VT double-buffered [2][64 d][128B] (transposed V) + PB [4 waves][16 q][128B].
__global__ __launch_bounds__(256) void attn_mfma(
    const unsigned short* __restrict__ qkvb,
    const unsigned* __restrict__ Jwpk,
    const unsigned* __restrict__ rdMpk,
    const float* __restrict__ bias_scale,
    unsigned short* __restrict__ attnb)
{
  __shared__ __align__(16) unsigned char smem[24576];
  unsigned char* VT = smem;              // 2 x 8192
  unsigned char* PB = smem + 16384;      // 8192

  const int gid = blockIdx.x;
  const int bh = gid & 31;
  const int c = (gid < 256) ? (15 - (gid >> 5)) : ((gid - 256) >> 5);  // LPT
  const int b = bh >> 4, h = bh & 15;
  const int tid = threadIdx.x;
  const int w = tid >> 6;
  const int lane = tid & 63;
  const int lr = lane & 15;
  const int g = lane >> 4;
  const int t0 = c * 64;
  const int nT = c + 1;

  const unsigned short* Qb = qkvb + (size_t)b * T_ * 3072 + h * 64;
  const unsigned short* Kb = Qb + 1024;
  const unsigned short* Vb = Qb + 2048;
  const size_t jb = (size_t)(b * H_ + h) * T_;

  // Q fragments: direct global (scale folded into logits later)
  bf16x8 qa[2];
  {
    const size_t qr = (size_t)(t0 + w * 16 + lr) * 3072;
#pragma unroll
    for (int kb = 0; kb < 2; ++kb)
      qa[kb] = *(const bf16x8*)(Qb + qr + kb * 32 + g * 8);
  }
  bf16x8 ra = *(const bf16x8*)(rdMpk + ((jb + t0 + w * 16 + lr) << 4) + g * 4);
  const float bsc = bias_scale[h];

  float m[4], lsum[4];
  f32x4 O[4];
  const f32x4 zf = {0.f, 0.f, 0.f, 0.f};
#pragma unroll
  for (int r = 0; r < 4; ++r) { m[r] = -1e30f; lsum[r] = 0.f; }
#pragma unroll
  for (int d = 0; d < 4; ++d) O[d] = zf;

  // V staging ids: thread (sp = s-pair 0..31, d8 = 0..7)
  const int sp = tid & 31, d8 = tid >> 5;
  uint4 v0, v1, v0n, v1n;
  {
    const size_t r0 = (size_t)(2 * sp) * 3072 + d8 * 8;  // tile 0: s0=0
    v0 = *(const uint4*)(Vb + r0);
    v1 = *(const uint4*)(Vb + r0 + 3072);
  }

  for (int ti = 0; ti < nT; ++ti) {
    const int s0 = ti * 64;
    // ---- write transposed V tile from regs (buf ti&1) ----
    {
      unsigned* vt = (unsigned*)(VT + (ti & 1) * 8192);
      const unsigned a[4] = {v0.x, v0.y, v0.z, v0.w};
      const unsigned bq[4] = {v1.x, v1.y, v1.z, v1.w};
#pragma unroll
      for (int i = 0; i < 8; ++i) {
        const int d = d8 * 8 + i;
        const unsigned dw = (i & 1)
            ? __builtin_amdgcn_perm(bq[i >> 1], a[i >> 1], 0x07060302)
            : __builtin_amdgcn_perm(bq[i >> 1], a[i >> 1], 0x05040100);
        vt[d * 32 + (sp ^ ((d & 7) << 2))] = dw;
      }
    }
    // prefetch next V tile (T14 issue-early)
    if (ti + 1 < nT) {
      const size_t rn = (size_t)(s0 + 64 + 2 * sp) * 3072 + d8 * 8;
      v0n = *(const uint4*)(Vb + rn);
      v1n = *(const uint4*)(Vb + rn + 3072);
    }
    __syncthreads();

    // ---- QK^T + bias via MFMA (K and Jwpk direct from global) ----
    f32x4 S[4], Sb[4];
#pragma unroll
    for (int cb = 0; cb < 4; ++cb) {
      const size_t srow = (size_t)(s0 + cb * 16 + lr);
      f32x4 a = zf;
#pragma unroll
      for (int kb = 0; kb < 2; ++kb) {
        const bf16x8 kf = *(const bf16x8*)(Kb + srow * 3072 + kb * 32 + g * 8);
        a = __builtin_amdgcn_mfma_f32_16x16x32_bf16(qa[kb], kf, a, 0, 0, 0);
      }
      S[cb] = a;
      const bf16x8 jw = *(const bf16x8*)(Jwpk + ((jb + srow) << 4) + g * 4);
      Sb[cb] = __builtin_amdgcn_mfma_f32_16x16x32_bf16(ra, jw, zf, 0, 0, 0);
    }

    // ---- online softmax ----
    const bool diag = (s0 == t0);
    float logit[4][4];
#pragma unroll
    for (int cb = 0; cb < 4; ++cb) {
#pragma unroll
      for (int r = 0; r < 4; ++r) {
        float lg = S[cb][r] * 0.125f + fabsf(Sb[cb][r]) * bsc;
        if (diag && (cb * 16 + lr > w * 16 + 4 * g + r)) lg = -1e30f;
        logit[cb][r] = lg;
      }
    }
#pragma unroll
    for (int r = 0; r < 4; ++r) {
      float mx = fmaxf(fmaxf(logit[0][r], logit[1][r]), fmaxf(logit[2][r], logit[3][r]));
      mx = fmaxf(mx, __shfl_xor(mx, 1));
      mx = fmaxf(mx, __shfl_xor(mx, 2));
      mx = fmaxf(mx, __shfl_xor(mx, 4));
      mx = fmaxf(mx, __shfl_xor(mx, 8));
      const float nm = fmaxf(m[r], mx);
      const float sc = __expf(m[r] - nm);
      m[r] = nm;
      lsum[r] *= sc;
#pragma unroll
      for (int d = 0; d < 4; ++d) O[d][r] *= sc;
    }
#pragma unroll
    for (int cb = 0; cb < 4; ++cb) {
#pragma unroll
      for (int r = 0; r < 4; ++r) {
        const float p = __expf(logit[cb][r] - m[r]);
        lsum[r] += p;
        const int q = 4 * g + r;
        const int s = cb * 16 + lr;
        const int byte = w * 2048 + q * 128 + ((2 * s) ^ ((q & 7) << 4));
        *(unsigned short*)(PB + byte) = f2bf(p);
      }
    }
    asm volatile("s_waitcnt lgkmcnt(0)" ::: "memory");
    __builtin_amdgcn_sched_barrier(0);

    // ---- PV via MFMA (VT reads, 2-way-free swizzle) ----
    bf16x8 pa[2];
#pragma unroll
    for (int kb = 0; kb < 2; ++kb) {
      const int byte = w * 2048 + lr * 128 + (((kb * 64) + 16 * g) ^ ((lr & 7) << 4));
      pa[kb] = *(const bf16x8*)(PB + byte);
    }
    const unsigned char* vtb = VT + (ti & 1) * 8192;
#pragma unroll
    for (int db = 0; db < 4; ++db) {
      const int d = db * 16 + lr;
#pragma unroll
      for (int kb = 0; kb < 2; ++kb) {
        const int byte = d * 128 + (((kb * 64) + 16 * g) ^ ((d & 7) << 4));
        const bf16x8 vf = *(const bf16x8*)(vtb + byte);
        O[db] = __builtin_amdgcn_mfma_f32_16x16x32_bf16(pa[kb], vf, O[db], 0, 0, 0);
      }
    }
    v0 = v0n; v1 = v1n;
  }

  // ---- finalize ----
#pragma unroll
  for (int r = 0; r < 4; ++r) {
    float l = lsum[r];
    l += __shfl_xor(l, 1);
    l += __shfl_xor(l, 2);
    l += __shfl_xor(l, 4);
    l += __shfl_xor(l, 8);
    lsum[r] = 1.f / l;
  }
  {
    const int qb = w * 16 + 4 * g;
#pragma unroll
    for (int db = 0; db < 4; ++db) {
#pragma unroll
      for (int r = 0; r < 4; ++r) {
        const int t = t0 + qb + r;
        attnb[(size_t)(b * T_ + t) * 1024 + h * 64 + db * 16 + lr] =
            f2bf(O[db][r] * lsum[r]);
      }
    }
  }
}

// =============================== launcher ===============================
extern "C" void kernel_launch(void* const* d_in, const int* in_sizes, int n_in,
                              void* d_out, int out_size, void* d_ws, size_t ws_size,
                              hipStream_t stream)
{
  (void)in_sizes; (void)n_in; (void)out_size; (void)ws_size;
  const float* x    = (const float*)d_in[0];
  const float* Wqkv = (const float*)d_in[1];
  const float* bqkv = (const float*)d_in[2];
  const float* W1w  = (const float*)d_in[3];
  const float* W2w  = (const float*)d_in[4];
  const float* W1r  = (const float*)d_in[5];
  const float* W2r  = (const float*)d_in[6];
  const float* bsc  = (const float*)d_in[7];
  const float* Wout = (const float*)d_in[8];
  const float* bout = (const float*)d_in[9];
  float* out = (float*)d_out;

  unsigned short* xb    = (unsigned short*)d_ws;            // 2048*1024
  unsigned short* Wb    = xb + (size_t)2048 * 1024;         // 3328*1024
  unsigned short* Woutb = Wb + (size_t)3328 * 1024;         // 1024*1024
  unsigned short* qkvb  = Woutb + (size_t)1024 * 1024;      // 2048*3072
  unsigned short* attnb = qkvb + (size_t)2048 * 3072;       // 2048*1024
  float* linesf = (float*)(attnb + (size_t)2048 * 1024);    // 2048*256
  float* Jw     = linesf + (size_t)2048 * 256;              // 196608
  float* rd     = Jw + 196608;                              // 196608
  unsigned* Jwpk  = (unsigned*)(rd + 196608);               // 524288
  unsigned* rdMpk = Jwpk + 524288;                          // 524288

  convert_kernel<<<dim3(3200), 256, 0, stream>>>(
      x, Wqkv, W1w, W2w, W1r, W2r, Wout, xb, Wb, Woutb);
  gemm_qkv<<<dim3(832), 128, 0, stream>>>(xb, Wb, bqkv, qkvb, linesf);
  exterior_kernel<<<dim3(B_ * T_ * H_ / 256), 256, 0, stream>>>(
      linesf, Jw, rd, Jwpk);
  scan_kernel<<<dim3(B_ * H_), 256, 0, stream>>>(Jw, rd, rdMpk);
  attn_mfma<<<dim3(B_ * H_ * (T_ / 64)), 256, 0, stream>>>(
      qkvb, Jwpk, rdMpk, bsc, attnb);
  gemm_out<<<dim3(256), 128, 0, stream>>>(attnb, Woutb, bout, out);
}

// Round 8
// 214.320 us; speedup vs baseline: 1.2140x; 1.2140x over previous
//
#include <hip/hip_runtime.h>
#include <math.h>

#define B_ 2
#define T_ 1024
#define D_ 1024
#define H_ 16

typedef __attribute__((ext_vector_type(8))) short bf16x8;
typedef __attribute__((ext_vector_type(4))) float f32x4;

__device__ inline unsigned short f2bf(float x) {
  return (unsigned short)((__float_as_uint(x) + 0x8000u) >> 16);
}
// pack two f32 -> dword of 2 bf16 (lo in low half)
__device__ inline unsigned bfpack(float lo, float hi) {
  unsigned a = __float_as_uint(hi) + 0x8000u;
  unsigned b = __float_as_uint(lo) + 0x8000u;
  return __builtin_amdgcn_perm(a, b, 0x07060302);
}
__device__ inline void hl_split(float x, unsigned short& h, unsigned short& l) {
  unsigned short hh = f2bf(x);
  float hf = __uint_as_float(((unsigned)hh) << 16);
  l = f2bf(x - hf);
  h = hh;
}

// ================= f32 -> bf16 conversion (x, concat-W, Wout) =================
#define CN1 2097152   // x
#define CN2 3407872   // Wb = [Wqkv;W1w;W2w;W1r;W2r] 3328x1024
#define CN3 1048576   // Wout
__global__ __launch_bounds__(256) void convert_kernel(
    const float* __restrict__ x, const float* __restrict__ Wqkv,
    const float* __restrict__ W1w, const float* __restrict__ W2w,
    const float* __restrict__ W1r, const float* __restrict__ W2r,
    const float* __restrict__ Wout,
    unsigned short* __restrict__ xb, unsigned short* __restrict__ Wb,
    unsigned short* __restrict__ Woutb)
{
  const long i8 = ((long)blockIdx.x * 256 + threadIdx.x) * 8;
  const float* src;
  unsigned short* dst;
  if (i8 < CN1) {
    src = x + i8; dst = xb + i8;
  } else if (i8 < CN1 + CN2) {
    const long j = i8 - CN1;
    const int row = (int)(j >> 10), col = (int)(j & 1023);
    if (row < 3072) src = Wqkv + (size_t)row * 1024 + col;
    else {
      const int r = row - 3072;
      const float* Wm = (r < 64) ? W1w : (r < 128) ? W2w : (r < 192) ? W1r : W2r;
      src = Wm + (size_t)(r & 63) * 1024 + col;
    }
    dst = Wb + j;
  } else {
    const long j = i8 - CN1 - CN2;
    src = Wout + j; dst = Woutb + j;
  }
  const float4 v0 = *(const float4*)src;
  const float4 v1 = *(const float4*)(src + 4);
  uint4 o;
  o.x = bfpack(v0.x, v0.y); o.y = bfpack(v0.z, v0.w);
  o.z = bfpack(v1.x, v1.y); o.w = bfpack(v1.z, v1.w);
  *(uint4*)dst = o;
}

// ===== bf16 MFMA GEMM core: 128x128 tile, 256 threads (2x2 waves), BK=32, dbuf =====
// LDS slot-major per buf: [4 slot(8-short)][128 row][16B] = 8KB; A bufs at 0/8K, B at 16K/24K.
#define G_PRO()                                                                \
  const int tid = threadIdx.x;                                                 \
  const int w = tid >> 6, lane = tid & 63;                                     \
  const int lr = lane & 15, g = lane >> 4;                                     \
  const int wm = (w >> 1) * 64, wn = (w & 1) * 64;                             \
  const int row = tid >> 1, half = tid & 1;

#define G_LOADA(d, s) {                                                        \
  d[0] = *(const uint4*)(Ap + (s) * 32);                                       \
  d[1] = *(const uint4*)(Ap + (s) * 32 + 8); }
#define G_LOADB(d, s) {                                                        \
  d[0] = *(const uint4*)(Bp + (s) * 32);                                       \
  d[1] = *(const uint4*)(Bp + (s) * 32 + 8); }
#define G_STORE(bi, a, b) {                                                    \
  unsigned char* SA_ = Smem + (bi) * 8192;                                     \
  *(uint4*)(SA_ + (half * 2 + 0) * 2048 + row * 16) = a[0];                    \
  *(uint4*)(SA_ + (half * 2 + 1) * 2048 + row * 16) = a[1];                    \
  unsigned char* SB_ = Smem + 16384 + (bi) * 8192;                             \
  *(uint4*)(SB_ + (half * 2 + 0) * 2048 + row * 16) = b[0];                    \
  *(uint4*)(SB_ + (half * 2 + 1) * 2048 + row * 16) = b[1]; }
#define G_COMPUTE(bi) {                                                        \
  const unsigned char* SA_ = Smem + (bi) * 8192;                               \
  const unsigned char* SB_ = Smem + 16384 + (bi) * 8192;                       \
  bf16x8 af[4], bfr[4];                                                        \
  _Pragma("unroll") for (int i = 0; i < 4; ++i)                                \
    af[i] = *(const bf16x8*)(SA_ + g * 2048 + (wm + i * 16 + lr) * 16);        \
  _Pragma("unroll") for (int j = 0; j < 4; ++j)                                \
    bfr[j] = *(const bf16x8*)(SB_ + g * 2048 + (wn + j * 16 + lr) * 16);       \
  _Pragma("unroll") for (int i = 0; i < 4; ++i)                                \
  _Pragma("unroll") for (int j = 0; j < 4; ++j)                                \
    acc[i][j] = __builtin_amdgcn_mfma_f32_16x16x32_bf16(af[i], bfr[j],         \
                                                        acc[i][j], 0, 0, 0); }
#define G_MAIN()                                                               \
  f32x4 acc[4][4];                                                             \
  const f32x4 zf = {0.f, 0.f, 0.f, 0.f};                                       \
  _Pragma("unroll") for (int i = 0; i < 4; ++i)                                \
  _Pragma("unroll") for (int j = 0; j < 4; ++j) acc[i][j] = zf;                \
  uint4 a0[2], b0[2], a1[2], b1[2];                                            \
  G_LOADA(a0, 0); G_LOADB(b0, 0);                                              \
  G_STORE(0, a0, b0);                                                          \
  G_LOADA(a1, 1); G_LOADB(b1, 1);                                              \
  __syncthreads();                                                             \
  _Pragma("unroll 1") for (int s = 0; s < 32; s += 2) {                        \
    G_COMPUTE(0);                                                              \
    G_STORE(1, a1, b1);                                                        \
    if (s + 2 < 32) { G_LOADA(a0, s + 2); G_LOADB(b0, s + 2); }                \
    __syncthreads();                                                           \
    G_COMPUTE(1);                                                              \
    if (s + 2 < 32) G_STORE(0, a0, b0);                                        \
    if (s + 3 < 32) { G_LOADA(a1, s + 3); G_LOADB(b1, s + 3); }                \
    __syncthreads();                                                           \
  }

// qkv GEMM: [2048,3328] = xb @ Wb^T; cols<3072 -> qkvb (bf16 +bias, LDS-transposed
// uint4 stores), cols>=3072 -> linesf (f32 scalar stores, no amplification).
__global__ __launch_bounds__(256) void gemm_qkv(
    const unsigned short* __restrict__ Ab, const unsigned short* __restrict__ Bb,
    const float* __restrict__ bqkv,
    unsigned short* __restrict__ Cq, float* __restrict__ Clines)
{
  __shared__ __align__(16) unsigned char Smem[32768];
  const int bid = blockIdx.x;                    // 416 = 16m x 26n
  const int sid = (bid & 7) * 52 + (bid >> 3);   // bijective XCD swizzle
  const int m0 = (sid & 15) * 128, n0 = (sid >> 4) * 128;
  G_PRO();
  const unsigned short* Ap = Ab + (size_t)(m0 + row) * 1024 + half * 16;
  const unsigned short* Bp = Bb + (size_t)(n0 + row) * 1024 + half * 16;
  G_MAIN();

  __syncthreads();   // all LDS reads done; reuse Smem as C-tile [128][256B]
  if (n0 < 3072) {
#pragma unroll
    for (int i = 0; i < 4; ++i) {
#pragma unroll
      for (int j = 0; j < 4; ++j) {
        const int ccol = wn + j * 16 + lr;
#pragma unroll
        for (int r = 0; r < 4; ++r) {
          const float mine = acc[i][j][r] + bqkv[n0 + ccol];
          const float part = __shfl_xor(mine, 1);
          const unsigned pk = (lr & 1) ? bfpack(part, mine) : bfpack(mine, part);
          if ((lr & 1) == 0) {
            const int rrow = wm + i * 16 + 4 * g + r;
            *(unsigned*)(Smem + rrow * 256 + ccol * 2) = pk;
          }
        }
      }
    }
    __syncthreads();
#pragma unroll
    for (int p = 0; p < 8; ++p) {
      const int rrow = p * 16 + (tid >> 4);
      const int c16 = tid & 15;
      const uint4 v = *(const uint4*)(Smem + rrow * 256 + c16 * 16);
      *(uint4*)(Cq + (size_t)(m0 + rrow) * 3072 + n0 + c16 * 8) = v;
    }
  } else {
#pragma unroll
    for (int i = 0; i < 4; ++i) {
      const int rbase = m0 + wm + i * 16 + 4 * g;
#pragma unroll
      for (int j = 0; j < 4; ++j) {
        const int col = n0 - 3072 + wn + j * 16 + lr;
#pragma unroll
        for (int r = 0; r < 4; ++r)
          Clines[(size_t)(rbase + r) * 256 + col] = acc[i][j][r];
      }
    }
  }
}

// out GEMM: [2048,1024] f32 = attnb @ Woutb^T + bout (f32 scalar stores are clean)
__global__ __launch_bounds__(256) void gemm_out(
    const unsigned short* __restrict__ Ab, const unsigned short* __restrict__ Bb,
    const float* __restrict__ bias, float* __restrict__ C)
{
  __shared__ __align__(16) unsigned char Smem[32768];
  const int bid = blockIdx.x;                   // 128 = 16m x 8n
  const int sid = (bid & 7) * 16 + (bid >> 3);
  const int m0 = (sid & 15) * 128, n0 = (sid >> 4) * 128;
  G_PRO();
  const unsigned short* Ap = Ab + (size_t)(m0 + row) * 1024 + half * 16;
  const unsigned short* Bp = Bb + (size_t)(n0 + row) * 1024 + half * 16;
  G_MAIN();
#pragma unroll
  for (int i = 0; i < 4; ++i) {
    const int rbase = m0 + wm + i * 16 + 4 * g;
#pragma unroll
    for (int j = 0; j < 4; ++j) {
      const int col = n0 + wn + j * 16 + lr;
      const float bb = bias[col];
#pragma unroll
      for (int r = 0; r < 4; ++r)
        C[(size_t)(rbase + r) * 1024 + col] = acc[i][j][r] + bb;
    }
  }
}

// ============ exterior products + J6 permute from linesf ============
__global__ __launch_bounds__(256) void exterior_kernel(
    const float* __restrict__ linesf,
    float* __restrict__ Jw, float* __restrict__ rd,
    unsigned* __restrict__ Jwpk)
{
  const int i = blockIdx.x * 256 + threadIdx.x;   // 32768
  const int h = i & 15;
  const int t = (i >> 4) & 1023;
  const int b = i >> 14;
  const size_t rowt = ((size_t)(b * T_) + t) * 256;

  float4 p1w = make_float4(0.f, 0.f, 0.f, 0.f);
  if (t > 0) p1w = *(const float4*)(linesf + rowt - 256 + h * 4);
  const float4 p2w = *(const float4*)(linesf + rowt + 64 + h * 4);
  const float4 p1r = *(const float4*)(linesf + rowt + 128 + h * 4);
  const float4 p2r = *(const float4*)(linesf + rowt + 192 + h * 4);

  const size_t base = ((size_t)(b * H_ + h) * T_ + t) * 6;
  {
    const float L0 = p1w.x * p2w.y - p1w.y * p2w.x;
    const float L1 = p1w.x * p2w.z - p1w.z * p2w.x;
    const float L2 = p1w.x * p2w.w - p1w.w * p2w.x;
    const float L3 = p1w.y * p2w.z - p1w.z * p2w.y;
    const float L4 = p1w.y * p2w.w - p1w.w * p2w.y;
    const float L5 = p1w.z * p2w.w - p1w.w * p2w.z;
    const float n = sqrtf(L0 * L0 + L1 * L1 + L2 * L2 + L3 * L3 + L4 * L4 + L5 * L5);
    const float inv = 1.f / fmaxf(n, 1e-12f);
    float jv[6] = {L5 * inv, -L4 * inv, L3 * inv, L2 * inv, -L1 * inv, L0 * inv};
#pragma unroll
    for (int k = 0; k < 6; ++k) Jw[base + k] = jv[k];
    unsigned short JH[6], JL[6];
#pragma unroll
    for (int k = 0; k < 6; ++k) hl_split(jv[k], JH[k], JL[k]);
    unsigned* jp = Jwpk + (((size_t)(b * H_ + h) * T_ + t) << 4);
    unsigned h01 = JH[0] | ((unsigned)JH[1] << 16);
    unsigned h23 = JH[2] | ((unsigned)JH[3] << 16);
    unsigned h45 = JH[4] | ((unsigned)JH[5] << 16);
    jp[0] = h01; jp[1] = h23; jp[2] = h45;
    jp[3] = JL[0] | ((unsigned)JL[1] << 16);
    jp[4] = JL[2] | ((unsigned)JL[3] << 16);
    jp[5] = JL[4] | ((unsigned)JL[5] << 16);
    jp[6] = h01; jp[7] = h23; jp[8] = h45;
#pragma unroll
    for (int k = 9; k < 16; ++k) jp[k] = 0;
  }
  {
    const float L0 = p1r.x * p2r.y - p1r.y * p2r.x;
    const float L1 = p1r.x * p2r.z - p1r.z * p2r.x;
    const float L2 = p1r.x * p2r.w - p1r.w * p2r.x;
    const float L3 = p1r.y * p2r.z - p1r.z * p2r.y;
    const float L4 = p1r.y * p2r.w - p1r.w * p2r.y;
    const float L5 = p1r.z * p2r.w - p1r.w * p2r.z;
    const float n = sqrtf(L0 * L0 + L1 * L1 + L2 * L2 + L3 * L3 + L4 * L4 + L5 * L5);
    const float inv = 1.f / fmaxf(n, 1e-12f);
    rd[base + 0] = L0 * inv;
    rd[base + 1] = L1 * inv;
    rd[base + 2] = L2 * inv;
    rd[base + 3] = L3 * inv;
    rd[base + 4] = L4 * inv;
    rd[base + 5] = L5 * inv;
  }
}

// ============ causal 6x6 Gram cumsum (Hillis-Steele) + rd_M -> rdMpk ============
__global__ __launch_bounds__(256) void scan_kernel(
    const float* __restrict__ Jw, const float* __restrict__ rd,
    unsigned* __restrict__ rdMpk)
{
  __shared__ float sc[256][40];
  const int tid = threadIdx.x;
  const int bh = blockIdx.x;
  const float* Jb = Jw + (size_t)bh * T_ * 6;
  const float* Rb = rd + (size_t)bh * T_ * 6;
  const int t0 = tid * 4;

  float L[36], M[36];
#pragma unroll
  for (int i = 0; i < 36; ++i) L[i] = 0.f;
  for (int tt = 0; tt < 4; ++tt) {
    float j6[6];
#pragma unroll
    for (int i = 0; i < 6; ++i) j6[i] = Jb[(size_t)(t0 + tt) * 6 + i];
#pragma unroll
    for (int a = 0; a < 6; ++a)
#pragma unroll
      for (int c = 0; c < 6; ++c)
        L[a * 6 + c] = fmaf(j6[a], j6[c], L[a * 6 + c]);
  }
#pragma unroll
  for (int i = 0; i < 36; ++i) M[i] = L[i];
#pragma unroll
  for (int k = 0; k < 9; ++k)
    *(float4*)&sc[tid][k * 4] = make_float4(M[k*4], M[k*4+1], M[k*4+2], M[k*4+3]);
  __syncthreads();

  for (int off = 1; off < 256; off <<= 1) {
    float4 tmp[9];
    const bool act = (tid >= off);
    if (act) {
#pragma unroll
      for (int k = 0; k < 9; ++k) tmp[k] = *(const float4*)&sc[tid - off][k * 4];
    }
    __syncthreads();
    if (act) {
#pragma unroll
      for (int k = 0; k < 9; ++k) {
        M[k*4]   += tmp[k].x; M[k*4+1] += tmp[k].y;
        M[k*4+2] += tmp[k].z; M[k*4+3] += tmp[k].w;
      }
#pragma unroll
      for (int k = 0; k < 9; ++k)
        *(float4*)&sc[tid][k * 4] = make_float4(M[k*4], M[k*4+1], M[k*4+2], M[k*4+3]);
    }
    __syncthreads();
  }

  float Mp[36];
#pragma unroll
  for (int i = 0; i < 36; ++i) Mp[i] = M[i] - L[i];   // exclusive prefix

  for (int tt = 0; tt < 4; ++tt) {
    const int t = t0 + tt;
    float j6[6], r6[6];
#pragma unroll
    for (int i = 0; i < 6; ++i) { j6[i] = Jb[(size_t)t * 6 + i]; r6[i] = Rb[(size_t)t * 6 + i]; }
#pragma unroll
    for (int a = 0; a < 6; ++a)
#pragma unroll
      for (int c = 0; c < 6; ++c)
        Mp[a * 6 + c] = fmaf(j6[a], j6[c], Mp[a * 6 + c]);
    float s6[6];
#pragma unroll
    for (int jj = 0; jj < 6; ++jj) {
      float s = 0.f;
#pragma unroll
      for (int a = 0; a < 6; ++a) s = fmaf(r6[a], Mp[a * 6 + jj], s);
      s6[jj] = s;
    }
    unsigned short hh[6], ll[6];
#pragma unroll
    for (int i = 0; i < 6; ++i) hl_split(s6[i], hh[i], ll[i]);
    unsigned* ob = rdMpk + (((size_t)bh * T_ + t) << 4);
    unsigned h01 = hh[0] | ((unsigned)hh[1] << 16);
    unsigned h23 = hh[2] | ((unsigned)hh[3] << 16);
    unsigned h45 = hh[4] | ((unsigned)hh[5] << 16);
    ob[0] = h01; ob[1] = h23; ob[2] = h45;
    ob[3] = h01; ob[4] = h23; ob[5] = h45;
    ob[6] = ll[0] | ((unsigned)ll[1] << 16);
    ob[7] = ll[2] | ((unsigned)ll[3] << 16);
    ob[8] = ll[4] | ((unsigned)ll[5] << 16);
#pragma unroll
    for (int i = 9; i < 16; ++i) ob[i] = 0;
  }
}

// ============ MFMA flash attention (bf16 qkv, direct-global K/Q/Jw) ============
__global__ __launch_bounds__(256) void attn_mfma(
    const unsigned short* __restrict__ qkvb,
    const unsigned* __restrict__ Jwpk,
    const unsigned* __restrict__ rdMpk,
    const float* __restrict__ bias_scale,
    unsigned short* __restrict__ attnb)
{
  __shared__ __align__(16) unsigned char smem[24576];
  unsigned char* VT = smem;              // 2 x 8192
  unsigned char* PB = smem + 16384;      // 8192

  const int gid = blockIdx.x;
  const int bh = gid & 31;
  const int c = (gid < 256) ? (15 - (gid >> 5)) : ((gid - 256) >> 5);  // LPT
  const int b = bh >> 4, h = bh & 15;
  const int tid = threadIdx.x;
  const int w = tid >> 6;
  const int lane = tid & 63;
  const int lr = lane & 15;
  const int g = lane >> 4;
  const int t0 = c * 64;
  const int nT = c + 1;

  const unsigned short* Qb = qkvb + (size_t)b * T_ * 3072 + h * 64;
  const unsigned short* Kb = Qb + 1024;
  const unsigned short* Vb = Qb + 2048;
  const size_t jb = (size_t)(b * H_ + h) * T_;

  bf16x8 qa[2];
  {
    const size_t qr = (size_t)(t0 + w * 16 + lr) * 3072;
#pragma unroll
    for (int kb = 0; kb < 2; ++kb)
      qa[kb] = *(const bf16x8*)(Qb + qr + kb * 32 + g * 8);
  }
  bf16x8 ra = *(const bf16x8*)(rdMpk + ((jb + t0 + w * 16 + lr) << 4) + g * 4);
  const float bsc = bias_scale[h];

  float m[4], lsum[4];
  f32x4 O[4];
  const f32x4 zf = {0.f, 0.f, 0.f, 0.f};
#pragma unroll
  for (int r = 0; r < 4; ++r) { m[r] = -1e30f; lsum[r] = 0.f; }
#pragma unroll
  for (int d = 0; d < 4; ++d) O[d] = zf;

  const int sp = tid & 31, d8 = tid >> 5;
  uint4 v0, v1, v0n, v1n;
  {
    const size_t r0 = (size_t)(2 * sp) * 3072 + d8 * 8;
    v0 = *(const uint4*)(Vb + r0);
    v1 = *(const uint4*)(Vb + r0 + 3072);
  }

  for (int ti = 0; ti < nT; ++ti) {
    const int s0 = ti * 64;
    {
      unsigned* vt = (unsigned*)(VT + (ti & 1) * 8192);
      const unsigned a[4] = {v0.x, v0.y, v0.z, v0.w};
      const unsigned bq[4] = {v1.x, v1.y, v1.z, v1.w};
#pragma unroll
      for (int i = 0; i < 8; ++i) {
        const int d = d8 * 8 + i;
        const unsigned dw = (i & 1)
            ? __builtin_amdgcn_perm(bq[i >> 1], a[i >> 1], 0x07060302)
            : __builtin_amdgcn_perm(bq[i >> 1], a[i >> 1], 0x05040100);
        vt[d * 32 + (sp ^ ((d & 7) << 2))] = dw;
      }
    }
    if (ti + 1 < nT) {
      const size_t rn = (size_t)(s0 + 64 + 2 * sp) * 3072 + d8 * 8;
      v0n = *(const uint4*)(Vb + rn);
      v1n = *(const uint4*)(Vb + rn + 3072);
    }
    __syncthreads();

    f32x4 S[4], Sb[4];
#pragma unroll
    for (int cb = 0; cb < 4; ++cb) {
      const size_t srow = (size_t)(s0 + cb * 16 + lr);
      f32x4 a = zf;
#pragma unroll
      for (int kb = 0; kb < 2; ++kb) {
        const bf16x8 kf = *(const bf16x8*)(Kb + srow * 3072 + kb * 32 + g * 8);
        a = __builtin_amdgcn_mfma_f32_16x16x32_bf16(qa[kb], kf, a, 0, 0, 0);
      }
      S[cb] = a;
      const bf16x8 jw = *(const bf16x8*)(Jwpk + ((jb + srow) << 4) + g * 4);
      Sb[cb] = __builtin_amdgcn_mfma_f32_16x16x32_bf16(ra, jw, zf, 0, 0, 0);
    }

    const bool diag = (s0 == t0);
    float logit[4][4];
#pragma unroll
    for (int cb = 0; cb < 4; ++cb) {
#pragma unroll
      for (int r = 0; r < 4; ++r) {
        float lg = S[cb][r] * 0.125f + fabsf(Sb[cb][r]) * bsc;
        if (diag && (cb * 16 + lr > w * 16 + 4 * g + r)) lg = -1e30f;
        logit[cb][r] = lg;
      }
    }
#pragma unroll
    for (int r = 0; r < 4; ++r) {
      float mx = fmaxf(fmaxf(logit[0][r], logit[1][r]), fmaxf(logit[2][r], logit[3][r]));
      mx = fmaxf(mx, __shfl_xor(mx, 1));
      mx = fmaxf(mx, __shfl_xor(mx, 2));
      mx = fmaxf(mx, __shfl_xor(mx, 4));
      mx = fmaxf(mx, __shfl_xor(mx, 8));
      const float nm = fmaxf(m[r], mx);
      const float sc = __expf(m[r] - nm);
      m[r] = nm;
      lsum[r] *= sc;
#pragma unroll
      for (int d = 0; d < 4; ++d) O[d][r] *= sc;
    }
#pragma unroll
    for (int cb = 0; cb < 4; ++cb) {
#pragma unroll
      for (int r = 0; r < 4; ++r) {
        const float p = __expf(logit[cb][r] - m[r]);
        lsum[r] += p;
        const int q = 4 * g + r;
        const int s = cb * 16 + lr;
        const int byte = w * 2048 + q * 128 + ((2 * s) ^ ((q & 7) << 4));
        *(unsigned short*)(PB + byte) = f2bf(p);
      }
    }
    asm volatile("s_waitcnt lgkmcnt(0)" ::: "memory");
    __builtin_amdgcn_sched_barrier(0);

    bf16x8 pa[2];
#pragma unroll
    for (int kb = 0; kb < 2; ++kb) {
      const int byte = w * 2048 + lr * 128 + (((kb * 64) + 16 * g) ^ ((lr & 7) << 4));
      pa[kb] = *(const bf16x8*)(PB + byte);
    }
    const unsigned char* vtb = VT + (ti & 1) * 8192;
#pragma unroll
    for (int db = 0; db < 4; ++db) {
      const int d = db * 16 + lr;
#pragma unroll
      for (int kb = 0; kb < 2; ++kb) {
        const int byte = d * 128 + (((kb * 64) + 16 * g) ^ ((d & 7) << 4));
        const bf16x8 vf = *(const bf16x8*)(vtb + byte);
        O[db] = __builtin_amdgcn_mfma_f32_16x16x32_bf16(pa[kb], vf, O[db], 0, 0, 0);
      }
    }
    v0 = v0n; v1 = v1n;
  }

#pragma unroll
  for (int r = 0; r < 4; ++r) {
    float l = lsum[r];
    l += __shfl_xor(l, 1);
    l += __shfl_xor(l, 2);
    l += __shfl_xor(l, 4);
    l += __shfl_xor(l, 8);
    lsum[r] = 1.f / l;
  }
  {
    const int qb = w * 16 + 4 * g;
#pragma unroll
    for (int db = 0; db < 4; ++db) {
#pragma unroll
      for (int r = 0; r < 4; ++r) {
        const int t = t0 + qb + r;
        const float val = O[db][r] * lsum[r];
        const float part = __shfl_xor(val, 1);
        const unsigned pk = (lr & 1) ? bfpack(part, val) : bfpack(val, part);
        if ((lr & 1) == 0)
          *(unsigned*)(attnb + (size_t)(b * T_ + t) * 1024 + h * 64 + db * 16 + lr) = pk;
      }
    }
  }
}

// =============================== launcher ===============================
extern "C" void kernel_launch(void* const* d_in, const int* in_sizes, int n_in,
                              void* d_out, int out_size, void* d_ws, size_t ws_size,
                              hipStream_t stream)
{
  (void)in_sizes; (void)n_in; (void)out_size; (void)ws_size;
  const float* x    = (const float*)d_in[0];
  const float* Wqkv = (const float*)d_in[1];
  const float* bqkv = (const float*)d_in[2];
  const float* W1w  = (const float*)d_in[3];
  const float* W2w  = (const float*)d_in[4];
  const float* W1r  = (const float*)d_in[5];
  const float* W2r  = (const float*)d_in[6];
  const float* bsc  = (const float*)d_in[7];
  const float* Wout = (const float*)d_in[8];
  const float* bout = (const float*)d_in[9];
  float* out = (float*)d_out;

  unsigned short* xb    = (unsigned short*)d_ws;            // 2048*1024
  unsigned short* Wb    = xb + (size_t)2048 * 1024;         // 3328*1024
  unsigned short* Woutb = Wb + (size_t)3328 * 1024;         // 1024*1024
  unsigned short* qkvb  = Woutb + (size_t)1024 * 1024;      // 2048*3072
  unsigned short* attnb = qkvb + (size_t)2048 * 3072;       // 2048*1024
  float* linesf = (float*)(attnb + (size_t)2048 * 1024);    // 2048*256
  float* Jw     = linesf + (size_t)2048 * 256;              // 196608
  float* rd     = Jw + 196608;                              // 196608
  unsigned* Jwpk  = (unsigned*)(rd + 196608);               // 524288
  unsigned* rdMpk = Jwpk + 524288;                          // 524288

  convert_kernel<<<dim3(3200), 256, 0, stream>>>(
      x, Wqkv, W1w, W2w, W1r, W2r, Wout, xb, Wb, Woutb);
  gemm_qkv<<<dim3(416), 256, 0, stream>>>(xb, Wb, bqkv, qkvb, linesf);
  exterior_kernel<<<dim3(B_ * T_ * H_ / 256), 256, 0, stream>>>(
      linesf, Jw, rd, Jwpk);
  scan_kernel<<<dim3(B_ * H_), 256, 0, stream>>>(Jw, rd, rdMpk);
  attn_mfma<<<dim3(B_ * H_ * (T_ / 64)), 256, 0, stream>>>(
      qkvb, Jwpk, rdMpk, bsc, attnb);
  gemm_out<<<dim3(128), 256, 0, stream>>>(attnb, Woutb, bout, out);
}